// Round 1
// baseline (1505.547 us; speedup 1.0000x reference)
//
#include <hip/hip_runtime.h>
#include <hip/hip_bf16.h>

typedef __hip_bfloat16 bf16;

#define CH      64
#define DWC     128
#define SDIM    512
#define SPATIAL (64*64*64)     // 262144
#define NB      2
#define NVOX    (NB*SPATIAL)

// f32 workspace offsets (in floats), after the two bf16 tensors
#define OFF_SMOD   0
#define OFF_POOLED 256
#define OFF_GATE   512
#define OFF_W1P    768
#define OFF_B1P    8960
#define OFF_W1S    9088
#define OFF_W3T    9216
#define OFF_W4P    17408
#define OFF_B4P    25600
#define OFF_W4S    25728
#define OFF_W5T    25856
// total 34048 floats

#define H_ELEMS ((size_t)NB * DWC * SPATIAL)      // 67,108,864
#define H_BYTES (H_ELEMS * 2)                      // 134,217,728

__device__ __forceinline__ float b2f(unsigned short u) {
    return __uint_as_float(((unsigned)u) << 16);
}
__device__ __forceinline__ float gelu_f(float x) {
    return 0.5f * x * (1.0f + erff(x * 0.70710678118654752f));
}

// ---------------- K0: tiny prep -----------------------------------------
__global__ void prep_kernel(const float* __restrict__ style,
                            const float* __restrict__ w1, const float* __restrict__ b1,
                            const float* __restrict__ mod_w,
                            const float* __restrict__ style_w, const float* __restrict__ style_b,
                            const float* __restrict__ w3,
                            const float* __restrict__ w4, const float* __restrict__ b4,
                            const float* __restrict__ w5,
                            const float* __restrict__ ln1w, const float* __restrict__ ln1b,
                            const float* __restrict__ ln2w, const float* __restrict__ ln2b,
                            float* __restrict__ wsf) {
    int t = threadIdx.x;   // 256 threads, 1 block
    // s * demod per (b, ch); zero pooled
    {
        int b = t >> 7, ch = t & 127;
        float s = style_b[ch];
        for (int i = 0; i < SDIM; ++i) s = fmaf(style[b*SDIM + i], style_w[ch*SDIM + i], s);
        float k2 = 0.f;
        for (int j = 0; j < 27; ++j) { float w = mod_w[ch*27 + j]; k2 = fmaf(w, w, k2); }
        wsf[OFF_SMOD + t]   = s * rsqrtf(fmaf(k2, s*s, 1e-8f));
        wsf[OFF_POOLED + t] = 0.f;
    }
    // folded weights + transposes
    for (int idx = t; idx < DWC*CH; idx += 256) {
        int o = idx >> 6, c = idx & 63;
        wsf[OFF_W1P + idx] = w1[idx] * ln1w[c];
        wsf[OFF_W4P + idx] = w4[idx] * ln2w[c];
        wsf[OFF_W3T + idx] = w3[c*DWC + o];   // w3t[ch][c] = w3[c][ch]
        wsf[OFF_W5T + idx] = w5[c*DWC + o];   // w5t[f][c]  = w5[c][f]
    }
    if (t < DWC) {
        float bb1 = b1[t], ss1 = 0.f, bb4 = b4[t], ss4 = 0.f;
        for (int c = 0; c < CH; ++c) {
            bb1 = fmaf(w1[t*CH + c], ln1b[c], bb1);
            ss1 = fmaf(w1[t*CH + c], ln1w[c], ss1);
            bb4 = fmaf(w4[t*CH + c], ln2b[c], bb4);
            ss4 = fmaf(w4[t*CH + c], ln2w[c], ss4);
        }
        wsf[OFF_B1P + t] = bb1; wsf[OFF_W1S + t] = ss1;
        wsf[OFF_B4P + t] = bb4; wsf[OFF_W4S + t] = ss4;
    }
}

// ---------------- K1: LN1 + pw1 -> h (bf16) -----------------------------
__global__ __launch_bounds__(256) void ln_pw1_kernel(const float* __restrict__ inp,
                                                     const float* __restrict__ wsf,
                                                     bf16* __restrict__ h) {
    int gv = blockIdx.x * 256 + threadIdx.x;
    int b = gv >> 18;
    int v = gv & (SPATIAL - 1);
    const float* xin = inp + (size_t)b * CH * SPATIAL + v;
    float x[CH];
    float sum = 0.f, sumsq = 0.f;
    #pragma unroll
    for (int c = 0; c < CH; ++c) {
        float t = xin[(size_t)c * SPATIAL];
        x[c] = t; sum += t; sumsq = fmaf(t, t, sumsq);
    }
    float m   = sum * (1.f / CH);
    float var = fmaxf((sumsq - (float)CH * m * m) * (1.f / (CH - 1)), 0.f);
    float inv = 1.f / (sqrtf(var) + 1e-6f);

    const float* w1p = wsf + OFF_W1P;
    const float* b1p = wsf + OFF_B1P;
    const float* w1s = wsf + OFF_W1S;
    bf16* hout = h + (size_t)b * DWC * SPATIAL + v;

    #pragma unroll 1
    for (int o = 0; o < DWC; o += 4) {
        float a0 = 0.f, a1 = 0.f, a2 = 0.f, a3 = 0.f;
        #pragma unroll
        for (int c = 0; c < CH; ++c) {
            float xc = x[c];
            a0 = fmaf(w1p[(o+0)*CH + c], xc, a0);
            a1 = fmaf(w1p[(o+1)*CH + c], xc, a1);
            a2 = fmaf(w1p[(o+2)*CH + c], xc, a2);
            a3 = fmaf(w1p[(o+3)*CH + c], xc, a3);
        }
        hout[(size_t)(o+0)*SPATIAL] = __float2bfloat16(b1p[o+0] + inv*(a0 - m*w1s[o+0]));
        hout[(size_t)(o+1)*SPATIAL] = __float2bfloat16(b1p[o+1] + inv*(a1 - m*w1s[o+1]));
        hout[(size_t)(o+2)*SPATIAL] = __float2bfloat16(b1p[o+2] + inv*(a2 - m*w1s[o+2]));
        hout[(size_t)(o+3)*SPATIAL] = __float2bfloat16(b1p[o+3] + inv*(a3 - m*w1s[o+3]));
    }
}

// ---------------- K2: depthwise 3x3x3 + mod scale + GELU -> a, pooled ---
#define TD 4
#define TH 4
#define PD 6
#define PH 6
#define PW 66
#define PWP 68

__global__ __launch_bounds__(256) void conv_kernel(const bf16* __restrict__ h,
                                                   const float* __restrict__ mod_w,
                                                   const float* __restrict__ mod_b,
                                                   const float* __restrict__ wsf,
                                                   bf16* __restrict__ a,
                                                   float* __restrict__ pooled) {
    __shared__ unsigned short tile[PD*PH*PWP];
    __shared__ float part[4];
    int tid  = threadIdx.x;
    int bidx = blockIdx.x;                 // [0, NB*16*16)
    int b  = bidx >> 8;
    int d0 = ((bidx >> 4) & 15) * TD;
    int h0 = (bidx & 15) * TH;
    int w    = tid & 63;
    int hl   = tid >> 6;                   // 0..3  (also wave id)
    int lane = tid & 63;

    const unsigned short* hraw = (const unsigned short*)h;

    for (int ch = 0; ch < DWC; ++ch) {
        const unsigned short* hc = hraw + (size_t)(b*DWC + ch) * SPATIAL;
        // ---- stage tile (with halo, zero padded) ----
        for (int i = tid; i < PD*PH*PW; i += 256) {
            int dd = i / (PH*PW);
            int r  = i - dd*(PH*PW);
            int hy = r / PW;
            int wx = r - hy*PW - 1;
            int gd = d0 - 1 + dd;
            int gh = h0 - 1 + hy;
            unsigned short val = 0;
            if ((unsigned)gd < 64u && (unsigned)gh < 64u && (unsigned)wx < 64u)
                val = hc[(size_t)gd*4096 + gh*64 + wx];
            tile[dd*(PH*PWP) + hy*PWP + (wx + 1)] = val;
        }
        __syncthreads();

        float wt[27];
        #pragma unroll
        for (int j = 0; j < 27; ++j) wt[j] = mod_w[ch*27 + j];

        float acc0 = 0.f, acc1 = 0.f, acc2 = 0.f, acc3 = 0.f;
        #pragma unroll
        for (int dy = 0; dy < 3; ++dy) {
            #pragma unroll
            for (int dx = 0; dx < 3; ++dx) {
                int base = (hl + dy) * PWP + (w + dx);
                float c0 = b2f(tile[0*(PH*PWP) + base]);
                float c1 = b2f(tile[1*(PH*PWP) + base]);
                float c2 = b2f(tile[2*(PH*PWP) + base]);
                float c3 = b2f(tile[3*(PH*PWP) + base]);
                float c4 = b2f(tile[4*(PH*PWP) + base]);
                float c5 = b2f(tile[5*(PH*PWP) + base]);
                float w0 = wt[0*9 + dy*3 + dx];
                float w1_ = wt[1*9 + dy*3 + dx];
                float w2 = wt[2*9 + dy*3 + dx];
                acc0 = fmaf(w0, c0, fmaf(w1_, c1, fmaf(w2, c2, acc0)));
                acc1 = fmaf(w0, c1, fmaf(w1_, c2, fmaf(w2, c3, acc1)));
                acc2 = fmaf(w0, c2, fmaf(w1_, c3, fmaf(w2, c4, acc2)));
                acc3 = fmaf(w0, c3, fmaf(w1_, c4, fmaf(w2, c5, acc3)));
            }
        }

        float sm = wsf[OFF_SMOD + b*DWC + ch];
        float mb = mod_b[ch];
        size_t abase = (size_t)(b*DWC + ch) * SPATIAL + (size_t)(h0 + hl)*64 + w;
        float g0 = gelu_f(fmaf(acc0, sm, mb));
        float g1 = gelu_f(fmaf(acc1, sm, mb));
        float g2 = gelu_f(fmaf(acc2, sm, mb));
        float g3 = gelu_f(fmaf(acc3, sm, mb));
        a[abase + (size_t)(d0+0)*4096] = __float2bfloat16(g0);
        a[abase + (size_t)(d0+1)*4096] = __float2bfloat16(g1);
        a[abase + (size_t)(d0+2)*4096] = __float2bfloat16(g2);
        a[abase + (size_t)(d0+3)*4096] = __float2bfloat16(g3);

        float lsum = (g0 + g1) + (g2 + g3);
        #pragma unroll
        for (int off = 32; off > 0; off >>= 1) lsum += __shfl_down(lsum, off, 64);
        if (lane == 0) part[hl] = lsum;
        __syncthreads();
        if (tid == 0) atomicAdd(&pooled[b*DWC + ch], (part[0]+part[1])+(part[2]+part[3]));
    }
}

// ---------------- K3: SCA gate ------------------------------------------
__global__ void gate_kernel(const float* __restrict__ sca_w,
                            const float* __restrict__ sca_b,
                            float* __restrict__ wsf) {
    int t = threadIdx.x;                  // 256
    int b = t >> 7, o = t & 127;
    const float invS = 1.f / (float)SPATIAL;
    float g = sca_b[o];
    for (int i = 0; i < DWC; ++i)
        g = fmaf(sca_w[o*DWC + i], wsf[OFF_POOLED + b*DWC + i] * invS, g);
    wsf[OFF_GATE + t] = g;
}

// ---------------- K4: gate*, pw3, residual, LN2, pw4, GELU, pw5, out ----
__global__ __launch_bounds__(256) void tail_kernel(const float* __restrict__ inp,
                                                   const bf16* __restrict__ a,
                                                   const float* __restrict__ b3,
                                                   const float* __restrict__ b5,
                                                   const float* __restrict__ beta,
                                                   const float* __restrict__ gamma,
                                                   const float* __restrict__ wsf,
                                                   float* __restrict__ out) {
    int gv = blockIdx.x * 256 + threadIdx.x;
    int b = gv >> 18;
    int v = gv & (SPATIAL - 1);

    const unsigned short* av = (const unsigned short*)a + (size_t)b * DWC * SPATIAL + v;
    const float* gate = wsf + OFF_GATE + b*DWC;
    const float* w3t  = wsf + OFF_W3T;

    float t[CH];
    #pragma unroll
    for (int c = 0; c < CH; ++c) t[c] = b3[c];

    #pragma unroll 1
    for (int cb = 0; cb < DWC; cb += 16) {
        unsigned short raw[16];
        #pragma unroll
        for (int j = 0; j < 16; ++j) raw[j] = av[(size_t)(cb + j) * SPATIAL];
        #pragma unroll
        for (int j = 0; j < 16; ++j) {
            float xch = b2f(raw[j]) * gate[cb + j];
            #pragma unroll
            for (int c = 0; c < CH; ++c) t[c] = fmaf(w3t[(cb + j)*CH + c], xch, t[c]);
        }
    }

    // y = inp + t*beta ; LN2 stats
    const float* xin = inp + (size_t)b * CH * SPATIAL + v;
    float sum = 0.f, sumsq = 0.f;
    #pragma unroll
    for (int c = 0; c < CH; ++c) {
        float yv = fmaf(t[c], beta[c], xin[(size_t)c * SPATIAL]);
        t[c] = yv; sum += yv; sumsq = fmaf(yv, yv, sumsq);
    }
    float m2   = sum * (1.f / CH);
    float var2 = fmaxf((sumsq - (float)CH * m2 * m2) * (1.f / (CH - 1)), 0.f);
    float inv2 = 1.f / (sqrtf(var2) + 1e-6f);

    const float* w4p = wsf + OFF_W4P;
    const float* b4p = wsf + OFF_B4P;
    const float* w4s = wsf + OFF_W4S;
    const float* w5t = wsf + OFF_W5T;

    float acc[CH];
    #pragma unroll
    for (int c = 0; c < CH; ++c) acc[c] = b5[c];

    #pragma unroll 1
    for (int f = 0; f < DWC; f += 4) {
        float u0 = 0.f, u1 = 0.f, u2 = 0.f, u3 = 0.f;
        #pragma unroll
        for (int c = 0; c < CH; ++c) {
            float yv = t[c];
            u0 = fmaf(w4p[(f+0)*CH + c], yv, u0);
            u1 = fmaf(w4p[(f+1)*CH + c], yv, u1);
            u2 = fmaf(w4p[(f+2)*CH + c], yv, u2);
            u3 = fmaf(w4p[(f+3)*CH + c], yv, u3);
        }
        float g0 = gelu_f(fmaf(inv2, u0 - m2*w4s[f+0], b4p[f+0]));
        float g1 = gelu_f(fmaf(inv2, u1 - m2*w4s[f+1], b4p[f+1]));
        float g2 = gelu_f(fmaf(inv2, u2 - m2*w4s[f+2], b4p[f+2]));
        float g3 = gelu_f(fmaf(inv2, u3 - m2*w4s[f+3], b4p[f+3]));
        #pragma unroll
        for (int c = 0; c < CH; ++c) {
            float a_ = acc[c];
            a_ = fmaf(w5t[(f+0)*CH + c], g0, a_);
            a_ = fmaf(w5t[(f+1)*CH + c], g1, a_);
            a_ = fmaf(w5t[(f+2)*CH + c], g2, a_);
            a_ = fmaf(w5t[(f+3)*CH + c], g3, a_);
            acc[c] = a_;
        }
    }

    float* op = out + (size_t)b * CH * SPATIAL + v;
    #pragma unroll
    for (int c = 0; c < CH; ++c)
        op[(size_t)c * SPATIAL] = fmaf(acc[c], gamma[c], t[c]);
}

// ---------------- host launcher -----------------------------------------
extern "C" void kernel_launch(void* const* d_in, const int* in_sizes, int n_in,
                              void* d_out, int out_size, void* d_ws, size_t ws_size,
                              hipStream_t stream) {
    const float* inp     = (const float*)d_in[0];
    const float* style   = (const float*)d_in[1];
    const float* w1      = (const float*)d_in[2];
    const float* b1      = (const float*)d_in[3];
    const float* mod_w   = (const float*)d_in[4];
    const float* mod_b   = (const float*)d_in[5];
    const float* style_w = (const float*)d_in[6];
    const float* style_b = (const float*)d_in[7];
    const float* sca_w   = (const float*)d_in[8];
    const float* sca_b   = (const float*)d_in[9];
    const float* w3      = (const float*)d_in[10];
    const float* b3      = (const float*)d_in[11];
    const float* w4      = (const float*)d_in[12];
    const float* b4      = (const float*)d_in[13];
    const float* w5      = (const float*)d_in[14];
    const float* b5      = (const float*)d_in[15];
    const float* ln1w    = (const float*)d_in[16];
    const float* ln1b    = (const float*)d_in[17];
    const float* ln2w    = (const float*)d_in[18];
    const float* ln2b    = (const float*)d_in[19];
    const float* beta    = (const float*)d_in[20];
    const float* gamma   = (const float*)d_in[21];

    bf16*  h   = (bf16*)d_ws;
    bf16*  a   = (bf16*)((char*)d_ws + H_BYTES);
    float* wsf = (float*)((char*)d_ws + 2*H_BYTES);
    float* out = (float*)d_out;

    prep_kernel<<<1, 256, 0, stream>>>(style, w1, b1, mod_w, style_w, style_b,
                                       w3, w4, b4, w5, ln1w, ln1b, ln2w, ln2b, wsf);
    ln_pw1_kernel<<<NVOX/256, 256, 0, stream>>>(inp, wsf, h);
    conv_kernel<<<NB*16*16, 256, 0, stream>>>(h, mod_w, mod_b, wsf, a, wsf + OFF_POOLED);
    gate_kernel<<<1, 256, 0, stream>>>(sca_w, sca_b, wsf);
    tail_kernel<<<NVOX/256, 256, 0, stream>>>(inp, a, b3, b5, beta, gamma, wsf, out);
}